// Round 9
// baseline (183.872 us; speedup 1.0000x reference)
//
#include <hip/hip_runtime.h>

typedef unsigned short u16;
typedef unsigned int u32;
typedef __bf16 bf16x8 __attribute__((ext_vector_type(8)));
typedef float f32x4 __attribute__((ext_vector_type(4)));

__device__ __forceinline__ u16 f2bf(float f) {
    union { float f; u32 u; } v;
    v.f = f;
    u32 r = v.u + 0x7fffu + ((v.u >> 16) & 1u);
    return (u16)(r >> 16);
}

__device__ __forceinline__ u32 fbits(float f) {
    union { float f; u32 u; } v; v.f = f; return v.u;
}

__device__ __forceinline__ void glds16(const void* g, void* l) {
    __builtin_amdgcn_global_load_lds(
        (__attribute__((address_space(1))) unsigned int*)(g),
        (__attribute__((address_space(3))) unsigned int*)(l), 16, 0, 0);
}

#define MFMA __builtin_amdgcn_mfma_f32_16x16x32_bf16

// ---------------- fused cast fp32 -> bf16 + cos/sin float2 table ----------------
__global__ void castbf3(const float* __restrict__ a, u16* __restrict__ oa,
                        const float* __restrict__ b, u16* __restrict__ ob,
                        const float* __restrict__ c, u16* __restrict__ oc,
                        const float* __restrict__ fcos, const float* __restrict__ fsin,
                        float2* __restrict__ csb) {
    int blk = blockIdx.x;
    if (blk < 4096) {
        int i = blk * 256 + threadIdx.x;
        float4 v = ((const float4*)a)[i];
        ushort4 o;
        o.x = f2bf(v.x); o.y = f2bf(v.y); o.z = f2bf(v.z); o.w = f2bf(v.w);
        ((ushort4*)oa)[i] = o;
    } else if (blk < 7168) {
        int i = (blk - 4096) * 256 + threadIdx.x;   // float4 index over (3072,1024)
        int n = i >> 8, c4 = i & 255;
        int np;
        if (n < 2048) {
            int part = n >> 10, rem = n & 1023;
            int h = rem >> 6, d = rem & 63;
            int nd = (d >> 1) + ((d & 1) << 5);
            np = part * 1024 + h * 64 + nd;
        } else np = n;
        float4 v = ((const float4*)b)[i];
        ushort4 o;
        o.x = f2bf(v.x); o.y = f2bf(v.y); o.z = f2bf(v.z); o.w = f2bf(v.w);
        ((ushort4*)ob)[np * 256 + c4] = o;
    } else if (blk < 8192) {
        int i = (blk - 7168) * 256 + threadIdx.x;
        float4 v = ((const float4*)c)[i];
        ushort4 o;
        o.x = f2bf(v.x); o.y = f2bf(v.y); o.z = f2bf(v.z); o.w = f2bf(v.w);
        ((ushort4*)oc)[i] = o;
    } else {
        int i = (blk - 8192) * 256 + threadIdx.x;   // 0..65535 over (2048 t, 32 freq)
        csb[i] = make_float2(fcos[i], fsin[i]);
    }
}

// ---------------- QKV GEMM (128x128), r0 proven K-loop + XCD-chunked swizzle ---------
// (r7 form, unchanged)
__global__ __launch_bounds__(256) void gemm_qkv(
    const u16* __restrict__ A, const u16* __restrict__ B,
    const float2* __restrict__ csb,
    const float* __restrict__ qw, const float* __restrict__ kw,
    u16* __restrict__ q, u16* __restrict__ k, u16* __restrict__ vt)
{
    __shared__ alignas(16) u16 SB[2 * 8192];     // buf b: A at b*8192 (+4096 = B); Es alias
    u16* Es = SB;
    const int tid = threadIdx.x;
    const int lane = tid & 63;
    const int wave = tid >> 6;

    // XCD-chunked block swizzle: bid%8 ~ XCD; each XCD gets bm-range of 8, bn-range of 12
    const int bid = blockIdx.y * 24 + blockIdx.x;    // 0..767
    const int xcd = bid & 7;
    const int t8  = bid >> 3;                        // 0..95
    const int bm = ((xcd >> 1) * 8 + t8 / 12) * 128;
    const int bn = ((xcd & 1) * 12 + t8 % 12) * 128;

    const int wm = (wave >> 1) * 64, wn = (wave & 1) * 64;
    const int ln = lane & 15, quad = lane >> 4;
    const int K = 1024;

    f32x4 acc[4][4] = {};

    const int srow = tid >> 2;
    const int scol = (tid & 3) * 8;
    const u16* gA = A + (size_t)(bm + srow) * K + scol;
    const u16* gB = B + (size_t)(bn + srow) * K + scol;

    auto stage = [&](int k0, int bf) {
        u16* lA = &SB[bf * 8192 + wave * 512];
        u16* lB = &SB[bf * 8192 + 4096 + wave * 512];
        glds16(gA + k0, lA);
        glds16(gA + (size_t)64 * K + k0, lA + 2048);
        glds16(gB + k0, lB);
        glds16(gB + (size_t)64 * K + k0, lB + 2048);
    };

    stage(0, 0);
    for (int it = 0; it < 32; ++it) {
        stage((((it + 1) & 31) << 5), (it + 1) & 1);
        asm volatile("s_waitcnt vmcnt(4)\n\ts_barrier" ::: "memory");

        const u16* Asb = &SB[(it & 1) * 8192];
        const u16* Bsb = Asb + 4096;
        bf16x8 af[4], bfr[4];
#pragma unroll
        for (int i = 0; i < 4; ++i)
            af[i] = *(const bf16x8*)&Asb[(wm + i * 16 + ln) * 32 + quad * 8];
#pragma unroll
        for (int j = 0; j < 4; ++j)
            bfr[j] = *(const bf16x8*)&Bsb[(wn + j * 16 + ln) * 32 + quad * 8];
#pragma unroll
        for (int i = 0; i < 4; ++i)
#pragma unroll
            for (int j = 0; j < 4; ++j)
                acc[i][j] = MFMA(af[i], bfr[j], acc[i][j], 0, 0, 0);

        asm volatile("s_barrier" ::: "memory");
    }
    asm volatile("s_waitcnt vmcnt(0)\n\ts_barrier" ::: "memory");

    // ---- epilogue ----
    const int part = bn >> 10;                       // 0=q 1=k 2=v
    const int headw = wave & 1;
    const int h0 = (bn & 1023) >> 6;
    const float SC = 0.18033688011112042f;           // 0.125 * log2(e)
    const int b = bm >> 11, tbase = bm & 2047;

    if (part == 2) {
#pragma unroll
        for (int i = 0; i < 4; ++i) {
            int tlb = wm + i * 16 + quad * 4;
#pragma unroll
            for (int j = 0; j < 4; ++j) {
                int d = j * 16 + ln;
                uint2 pk;
                pk.x = __builtin_amdgcn_perm(fbits(acc[i][j][1]), fbits(acc[i][j][0]), 0x07060302u);
                pk.y = __builtin_amdgcn_perm(fbits(acc[i][j][3]), fbits(acc[i][j][2]), 0x07060302u);
                *(uint2*)&Es[headw * 8192 + d * 128 + (tlb ^ (ln << 3))] = pk;
            }
        }
        __syncthreads();
#pragma unroll
        for (int c = 0; c < 8; ++c) {
            int cid = c * 256 + tid;
            int tc = cid & 15, d = (cid >> 4) & 63, hd = cid >> 10;
            uint4 v = *(const uint4*)&Es[hd * 8192 + d * 128 + ((tc ^ (d & 15)) << 3)];
            size_t dst = ((size_t)((b * 16 + h0 + hd) * 64 + d)) * 2048
                       + tbase + ((tc >> 3) << 6) + (((tc & 7) ^ (d & 7)) << 3);
            *(uint4*)&vt[dst] = v;
        }
        return;
    }

    const float* nw = (part == 0) ? qw : kw;
    float wv[4];
#pragma unroll
    for (int j = 0; j < 4; ++j) {
        int nd = j * 16 + ln;
        int od = ((nd & 31) << 1) | (nd >> 5);
        wv[j] = nw[od];
    }

    if (part == 0) {
#pragma unroll
        for (int i = 0; i < 4; ++i) {
            float oj[4][4];
#pragma unroll
            for (int r = 0; r < 4; ++r) {
                int tloc = wm + i * 16 + quad * 4 + r;
                int t = (bm + tloc) & 2047;
                float v0 = acc[i][0][r], v1 = acc[i][1][r];
                float v2 = acc[i][2][r], v3 = acc[i][3][r];
                float ss = v0 * v0 + v1 * v1 + v2 * v2 + v3 * v3;
                ss += __shfl_xor(ss, 1);
                ss += __shfl_xor(ss, 2);
                ss += __shfl_xor(ss, 4);
                ss += __shfl_xor(ss, 8);
                float g = rsqrtf(ss * (1.0f / 64.0f) + 1e-6f) * SC;
                float x0a = v0 * g * wv[0], x0b = v1 * g * wv[1];
                float x1a = v2 * g * wv[2], x1b = v3 * g * wv[3];
                float2 cs0 = csb[t * 32 + ln];
                float2 cs1 = csb[t * 32 + 16 + ln];
                oj[0][r] = x0a * cs0.x - x1a * cs0.y;
                oj[2][r] = x0a * cs0.y + x1a * cs0.x;
                oj[1][r] = x0b * cs1.x - x1b * cs1.y;
                oj[3][r] = x0b * cs1.y + x1b * cs1.x;
            }
            int tlb = wm + i * 16 + quad * 4;
#pragma unroll
            for (int j = 0; j < 4; ++j) {
                uint2 pk;
                pk.x = __builtin_amdgcn_perm(fbits(oj[j][1]), fbits(oj[j][0]), 0x07060302u);
                pk.y = __builtin_amdgcn_perm(fbits(oj[j][3]), fbits(oj[j][2]), 0x07060302u);
                *(uint2*)&Es[headw * 8192 + (j * 16 + ln) * 128 + (tlb ^ (ln << 3))] = pk;
            }
        }
        __syncthreads();
#pragma unroll
        for (int c = 0; c < 8; ++c) {
            int cid = c * 256 + tid;
            int tc = cid & 15, d = (cid >> 4) & 63, hd = cid >> 10;
            uint4 v = *(const uint4*)&Es[hd * 8192 + d * 128 + ((tc ^ (d & 15)) << 3)];
            size_t dst = ((size_t)((b * 16 + h0 + hd) * 64 + d)) * 2048 + tbase + tc * 8;
            *(uint4*)&q[dst] = v;
        }
        return;
    }

    // K: RMSNorm + RoPE, [t][d] staging with quarter swizzle
#pragma unroll
    for (int i = 0; i < 4; ++i) {
#pragma unroll
        for (int r = 0; r < 4; ++r) {
            int tloc = wm + i * 16 + quad * 4 + r;
            int t = (bm + tloc) & 2047;

            float v0 = acc[i][0][r], v1 = acc[i][1][r];
            float v2 = acc[i][2][r], v3 = acc[i][3][r];
            float ss = v0 * v0 + v1 * v1 + v2 * v2 + v3 * v3;
            ss += __shfl_xor(ss, 1);
            ss += __shfl_xor(ss, 2);
            ss += __shfl_xor(ss, 4);
            ss += __shfl_xor(ss, 8);
            float g = rsqrtf(ss * (1.0f / 64.0f) + 1e-6f);

            float x0a = v0 * g * wv[0], x0b = v1 * g * wv[1];
            float x1a = v2 * g * wv[2], x1b = v3 * g * wv[3];
            float2 cs0 = csb[t * 32 + ln];
            float2 cs1 = csb[t * 32 + 16 + ln];
            float o0 = x0a * cs0.x - x1a * cs0.y;
            float o2 = x0a * cs0.y + x1a * cs0.x;
            float o1 = x0b * cs1.x - x1b * cs1.y;
            float o3 = x0b * cs1.y + x1b * cs1.x;

            u16* e = &Es[headw * 8192 + tloc * 64 + ln];
            e[((0 ^ quad) << 4)] = f2bf(o0);
            e[((1 ^ quad) << 4)] = f2bf(o1);
            e[((2 ^ quad) << 4)] = f2bf(o2);
            e[((3 ^ quad) << 4)] = f2bf(o3);
        }
    }
    __syncthreads();
#pragma unroll
    for (int c = 0; c < 8; ++c) {
        int cid = c * 256 + tid;
        int dc = cid & 7, tloc = (cid >> 3) & 127, hd = cid >> 10;
        int q2 = (tloc >> 2) & 3;
        int sq = (dc >> 1) ^ q2;
        uint4 v = *(const uint4*)&Es[hd * 8192 + tloc * 64 + sq * 16 + (dc & 1) * 8];
        int gm = bm + tloc;
        int bb = gm >> 11, t = gm & 2047;
        size_t rb = ((size_t)((bb * 16 + h0 + hd) * 2048 + t)) * 64;
        *(uint4*)&k[rb + ((dc ^ (t & 7)) << 3)] = v;
    }
}

// ---------------- 64x128 bf16 GEMM (projection), dbuf staging + XCD swizzle ----------
// (r7 form, unchanged)
__global__ __launch_bounds__(256) void gemm64(
    const u16* __restrict__ A, const u16* __restrict__ B,
    float* __restrict__ C, int M, int N, int K)
{
    __shared__ alignas(16) u16 SB[2 * 6144];
    const int tid = threadIdx.x;
    const int lane = tid & 63;
    const int wave = tid >> 6;

    const int bid = blockIdx.y * 8 + blockIdx.x;     // 0..511
    const int xcd = bid & 7;
    const int t8  = bid >> 3;                        // 0..63
    const int bm = (xcd * 8 + (t8 >> 3)) * 64;
    const int bn = (t8 & 7) * 128;

    const int wm = (wave >> 1) * 32, wn = (wave & 1) * 64;
    const int ln = lane & 15, quad = lane >> 4;

    f32x4 acc[2][4] = {};

    const int srow = tid >> 2;
    const int scol = (tid & 3) * 8;
    const u16* gA = A + (size_t)(bm + srow) * K + scol;
    const u16* gB = B + (size_t)(bn + srow) * K + scol;

    auto stage = [&](int k0, int bf) {
        u16* lA = &SB[bf * 6144 + wave * 512];
        u16* lB = &SB[bf * 6144 + 2048 + wave * 512];
        glds16(gA + k0, lA);
        glds16(gB + k0, lB);
        glds16(gB + (size_t)64 * K + k0, lB + 2048);
    };

    stage(0, 0);
    for (int it = 0; it < 32; ++it) {
        stage((((it + 1) & 31) << 5), (it + 1) & 1);
        asm volatile("s_waitcnt vmcnt(3)\n\ts_barrier" ::: "memory");

        const u16* Asb = &SB[(it & 1) * 6144];
        const u16* Bsb = Asb + 2048;
        bf16x8 af[2], bfr[4];
#pragma unroll
        for (int i = 0; i < 2; ++i)
            af[i] = *(const bf16x8*)&Asb[(wm + i * 16 + ln) * 32 + quad * 8];
#pragma unroll
        for (int j = 0; j < 4; ++j)
            bfr[j] = *(const bf16x8*)&Bsb[(wn + j * 16 + ln) * 32 + quad * 8];
#pragma unroll
        for (int i = 0; i < 2; ++i)
#pragma unroll
            for (int j = 0; j < 4; ++j)
                acc[i][j] = MFMA(af[i], bfr[j], acc[i][j], 0, 0, 0);

        asm volatile("s_barrier" ::: "memory");
    }

#pragma unroll
    for (int i = 0; i < 2; ++i) {
#pragma unroll
        for (int r = 0; r < 4; ++r) {
            int gm = bm + wm + i * 16 + quad * 4 + r;
            float* Crow = C + (size_t)gm * N + bn + wn + ln;
#pragma unroll
            for (int j = 0; j < 4; ++j)
                Crow[j * 16] = acc[i][j][r];
        }
    }
}

// ---------------- flash attention: K-staged, V DIRECT FROM L2 (m169 pattern) ---------
// r8's XCD-home made each head's V L2-resident (4 heads x 512 KB < 4 MB/XCD). V was
// staged to LDS then read 8x redundantly by the 8 waves -> half the LDS-pipe load.
// V is PRE-SWIZZLED in global (gemm_qkv epilogue), so the old swizzled LDS read
// indices map 1:1 to global addresses: Vs[d*64+c] == Vg[d*2048+jb+c]. Replace the
// LDS reads with direct global b128 loads, ISSUED BEFORE softmax (T14 issue-early:
// ~150cyc VALU covers L2 latency). Removes Vs (LDS 53->37 KB), halves LDS reads,
// halves DMA per iter. K stays LDS-staged (consumed right after the barrier).
__global__ __launch_bounds__(512) void attn_kernel(
    const u16* __restrict__ Q, const u16* __restrict__ K,
    const u16* __restrict__ VT, u16* __restrict__ Y)
{
    __shared__ alignas(16) u16 Ks[2][64 * 64];
    __shared__ alignas(16) u16 Ps[8][16 * 80];

    const int tid = threadIdx.x;
    const int lane = tid & 63;
    const int wave = tid >> 6;          // 0..7
    const int ln = lane & 15, quad = lane >> 4;

    const int lin = blockIdx.y * 16 + blockIdx.x;   // 0..511, dispatch-linear
    const int xcd = lin & 7;
    const int slot = lin >> 3;                      // 0..63
    const int pi = slot >> 2;                       // 0..15
    const int bh = xcd + ((slot & 3) << 3);         // 0..31: 4 heads per XCD

    const int qaIdx = pi, qbIdx = 31 - pi;
    const bool isB = wave >= 4;
    const int qidx = isB ? qbIdx : qaIdx;
    const int myq = qidx * 64 + (wave & 3) * 16;
    const size_t base = (size_t)bh * 2048 * 64;
    const u16* Kg = K + base;
    const u16* Vg = VT + base;
    const __bf16* Qg = (const __bf16*)(Q + base);   // (64 d, 2048 t) per head

    const int qt = myq + ln;
    bf16x8 qf0, qf1;
#pragma unroll
    for (int j = 0; j < 8; ++j) {
        qf0[j] = Qg[(size_t)(quad * 8 + j) * 2048 + qt];
        qf1[j] = Qg[(size_t)(32 + quad * 8 + j) * 2048 + qt];
    }

    f32x4 o[4] = {};
    float l = 0.0f;
    const int nstages = qbIdx + 1;
    const int sw = ln & 7;
    const int srow = wave * 8 + (lane >> 3);
    const int scol = (lane & 7) * 8;
    u16* Psw = &Ps[wave][0];

    // per-lane V row bases (pre-swizzled global layout; chunk indices as before)
    const size_t vro0 = (size_t)(quad ^ sw) * 8;
    const size_t vro1 = (size_t)((4 + quad) ^ sw) * 8;

    auto prefetch = [&](int jb, int nb) {
        glds16(&Kg[(size_t)(jb + srow) * 64 + scol], &Ks[nb][wave * 512]);
    };
    auto computeS = [&](f32x4* st, const u16* ksb) {
#pragma unroll
        for (int ct = 0; ct < 4; ++ct) {
            bf16x8 kf0 = *(const bf16x8*)&ksb[(ct * 16 + ln) * 64 + (quad ^ sw) * 8];
            bf16x8 kf1 = *(const bf16x8*)&ksb[(ct * 16 + ln) * 64 + ((4 + quad) ^ sw) * 8];
            f32x4 z = {};
            z = MFMA(kf0, qf0, z, 0, 0, 0);
            st[ct] = MFMA(kf1, qf1, z, 0, 0, 0);
        }
    };
    auto applyMask = [&](f32x4* st, int jb) {
        const int qg = myq + ln;
#pragma unroll
        for (int ct = 0; ct < 4; ++ct)
#pragma unroll
            for (int r = 0; r < 4; ++r)
                if (jb + ct * 16 + quad * 4 + r > qg) st[ct][r] = -1e30f;
    };

    // prologue: K tile 0 resident, S[0] in registers
    prefetch(0, 0);
    asm volatile("s_waitcnt vmcnt(0)\n\ts_barrier" ::: "memory");
    f32x4 st[4];
    computeS(st, &Ks[0][0]);
    if (qidx == 0) applyMask(st, 0);

    for (int jt = 0; jt < nstages; ++jt) {
        const bool haveNext = (jt + 1 < nstages);
        if (haveNext) prefetch((jt + 1) * 64, (jt + 1) & 1);

        const bool curActive = isB || jt <= qaIdx;
        if (curActive) {
            // issue V loads for tile jt early (direct from L2, pre-swizzled layout);
            // softmax VALU below hides the ~200cyc L2 latency.
            const int jb = jt * 64;
            bf16x8 vfr[8];
#pragma unroll
            for (int dt = 0; dt < 4; ++dt) {
                const u16* vrow = &Vg[(size_t)(dt * 16 + ln) * 2048 + jb];
                vfr[2 * dt]     = *(const bf16x8*)&vrow[vro0];
                vfr[2 * dt + 1] = *(const bf16x8*)&vrow[vro1];
            }

            float sum = 0.0f;
#pragma unroll
            for (int ct = 0; ct < 4; ++ct) {
                float e0 = exp2f(st[ct][0]), e1 = exp2f(st[ct][1]);
                float e2 = exp2f(st[ct][2]), e3 = exp2f(st[ct][3]);
                sum += (e0 + e1) + (e2 + e3);
                uint2 pk;
                pk.x = __builtin_amdgcn_perm(fbits(e1), fbits(e0), 0x07060302u);
                pk.y = __builtin_amdgcn_perm(fbits(e3), fbits(e2), 0x07060302u);
                *(uint2*)&Psw[ln * 80 + ct * 16 + quad * 4] = pk;
            }
            l += sum;   // per-lane partial; cross-quad reduce deferred to epilogue

            __builtin_amdgcn_s_waitcnt(0xC07F);  // lgkmcnt(0): own Ps writes visible
            bf16x8 pf0 = *(const bf16x8*)&Psw[ln * 80 + quad * 8];
            bf16x8 pf1 = *(const bf16x8*)&Psw[ln * 80 + 32 + quad * 8];
            __builtin_amdgcn_s_setprio(1);
#pragma unroll
            for (int dt = 0; dt < 4; ++dt) {
                o[dt] = MFMA(pf0, vfr[2 * dt], o[dt], 0, 0, 0);
                o[dt] = MFMA(pf1, vfr[2 * dt + 1], o[dt], 0, 0, 0);
            }
            __builtin_amdgcn_s_setprio(0);
        }

        // single barrier: own K DMA for tile jt+1 drained (V loads already consumed);
        // all waves past computeS(jt) -> next iter's prefetch may overwrite buf jt&1.
        asm volatile("s_waitcnt vmcnt(0)\n\ts_barrier" ::: "memory");

        const bool nextActive = haveNext && (isB || (jt + 1) <= qaIdx);
        if (nextActive) {
            __builtin_amdgcn_s_setprio(1);
            computeS(st, &Ks[(jt + 1) & 1][0]);
            __builtin_amdgcn_s_setprio(0);
            if (jt + 1 == qidx) applyMask(st, (jt + 1) * 64);
        }
    }

    // deferred l reduction: sum the 4 quad partials per q-column
    l += __shfl_xor(l, 16);
    l += __shfl_xor(l, 32);

    const int b = bh >> 4, h = bh & 15;
#pragma unroll
    for (int r = 0; r < 4; ++r) {
        float lr = __shfl(l, (lane & 48) + quad * 4 + r);
        float inv = 1.0f / lr;
        int gq = myq + quad * 4 + r;
        size_t yb = ((size_t)(b * 2048 + gq)) * 1024 + h * 64 + ln;
#pragma unroll
        for (int dt = 0; dt < 4; ++dt)
            Y[yb + dt * 16] = f2bf(o[dt][r] * inv);
    }
}

extern "C" void kernel_launch(void* const* d_in, const int* in_sizes, int n_in,
                              void* d_out, int out_size, void* d_ws, size_t ws_size,
                              hipStream_t stream) {
    const float* x      = (const float*)d_in[0];
    const float* fcos   = (const float*)d_in[1];
    const float* fsin   = (const float*)d_in[2];
    const float* w_attn = (const float*)d_in[3];
    const float* w_proj = (const float*)d_in[4];
    const float* qw     = (const float*)d_in[5];
    const float* kw     = (const float*)d_in[6];
    float* out = (float*)d_out;

    char* ws = (char*)d_ws;
    u16*    xb  = (u16*)(ws + 0);          //  8 MB  x bf16; aliased as yb after gemm_qkv
    u16*    yb  = (u16*)(ws + 0);
    u16*    wab = (u16*)(ws + 8388608);    //  6 MB  w_attn bf16 (q/k rows permuted)
    u16*    wpb = (u16*)(ws + 14680064);   //  2 MB  w_proj bf16
    u16*    qb  = (u16*)(ws + 16777216);   //  8 MB  q bf16 (B,H,64,2048), pre-scaled, perm-d
    u16*    kb  = (u16*)(ws + 25165824);   //  8 MB  k bf16 swizzled, perm-d
    u16*    vtb = (u16*)(ws + 33554432);   //  8 MB  v^T bf16 swizzled
    float2* csb = (float2*)(ws + 41943040);// 512 KB cos/sin interleaved table

    castbf3<<<8448, 256, 0, stream>>>(x, xb, w_attn, wab, w_proj, wpb, fcos, fsin, csb);

    gemm_qkv<<<dim3(24, 32), 256, 0, stream>>>(xb, wab, csb, qw, kw, qb, kb, vtb);

    attn_kernel<<<dim3(16, 32), 512, 0, stream>>>(qb, kb, vtb, yb);

    gemm64<<<dim3(8, 64), 256, 0, stream>>>(yb, wpb, out, 4096, 1024, 1024);
}

// Round 12
// 175.314 us; speedup vs baseline: 1.0488x; 1.0488x over previous
//
#include <hip/hip_runtime.h>

typedef unsigned short u16;
typedef unsigned int u32;
typedef __bf16 bf16x8 __attribute__((ext_vector_type(8)));
typedef float f32x4 __attribute__((ext_vector_type(4)));

__device__ __forceinline__ u16 f2bf(float f) {
    union { float f; u32 u; } v;
    v.f = f;
    u32 r = v.u + 0x7fffu + ((v.u >> 16) & 1u);
    return (u16)(r >> 16);
}

__device__ __forceinline__ u32 fbits(float f) {
    union { float f; u32 u; } v; v.f = f; return v.u;
}

__device__ __forceinline__ void glds16(const void* g, void* l) {
    __builtin_amdgcn_global_load_lds(
        (__attribute__((address_space(1))) unsigned int*)(g),
        (__attribute__((address_space(3))) unsigned int*)(l), 16, 0, 0);
}

#define MFMA __builtin_amdgcn_mfma_f32_16x16x32_bf16

// ---------------- fused cast fp32 -> bf16 + cos/sin float2 table ----------------
__global__ void castbf3(const float* __restrict__ a, u16* __restrict__ oa,
                        const float* __restrict__ b, u16* __restrict__ ob,
                        const float* __restrict__ c, u16* __restrict__ oc,
                        const float* __restrict__ fcos, const float* __restrict__ fsin,
                        float2* __restrict__ csb) {
    int blk = blockIdx.x;
    if (blk < 4096) {
        int i = blk * 256 + threadIdx.x;
        float4 v = ((const float4*)a)[i];
        ushort4 o;
        o.x = f2bf(v.x); o.y = f2bf(v.y); o.z = f2bf(v.z); o.w = f2bf(v.w);
        ((ushort4*)oa)[i] = o;
    } else if (blk < 7168) {
        int i = (blk - 4096) * 256 + threadIdx.x;   // float4 index over (3072,1024)
        int n = i >> 8, c4 = i & 255;
        int np;
        if (n < 2048) {
            int part = n >> 10, rem = n & 1023;
            int h = rem >> 6, d = rem & 63;
            int nd = (d >> 1) + ((d & 1) << 5);
            np = part * 1024 + h * 64 + nd;
        } else np = n;
        float4 v = ((const float4*)b)[i];
        ushort4 o;
        o.x = f2bf(v.x); o.y = f2bf(v.y); o.z = f2bf(v.z); o.w = f2bf(v.w);
        ((ushort4*)ob)[np * 256 + c4] = o;
    } else if (blk < 8192) {
        int i = (blk - 7168) * 256 + threadIdx.x;
        float4 v = ((const float4*)c)[i];
        ushort4 o;
        o.x = f2bf(v.x); o.y = f2bf(v.y); o.z = f2bf(v.z); o.w = f2bf(v.w);
        ((ushort4*)oc)[i] = o;
    } else {
        int i = (blk - 8192) * 256 + threadIdx.x;   // 0..65535 over (2048 t, 32 freq)
        csb[i] = make_float2(fcos[i], fsin[i]);
    }
}

// ---------------- QKV GEMM (128x128), r0 proven K-loop + XCD-chunked swizzle ---------
// (r7 form, unchanged)
__global__ __launch_bounds__(256) void gemm_qkv(
    const u16* __restrict__ A, const u16* __restrict__ B,
    const float2* __restrict__ csb,
    const float* __restrict__ qw, const float* __restrict__ kw,
    u16* __restrict__ q, u16* __restrict__ k, u16* __restrict__ vt)
{
    __shared__ alignas(16) u16 SB[2 * 8192];     // buf b: A at b*8192 (+4096 = B); Es alias
    u16* Es = SB;
    const int tid = threadIdx.x;
    const int lane = tid & 63;
    const int wave = tid >> 6;

    // XCD-chunked block swizzle: bid%8 ~ XCD; each XCD gets bm-range of 8, bn-range of 12
    const int bid = blockIdx.y * 24 + blockIdx.x;    // 0..767
    const int xcd = bid & 7;
    const int t8  = bid >> 3;                        // 0..95
    const int bm = ((xcd >> 1) * 8 + t8 / 12) * 128;
    const int bn = ((xcd & 1) * 12 + t8 % 12) * 128;

    const int wm = (wave >> 1) * 64, wn = (wave & 1) * 64;
    const int ln = lane & 15, quad = lane >> 4;
    const int K = 1024;

    f32x4 acc[4][4] = {};

    const int srow = tid >> 2;
    const int scol = (tid & 3) * 8;
    const u16* gA = A + (size_t)(bm + srow) * K + scol;
    const u16* gB = B + (size_t)(bn + srow) * K + scol;

    auto stage = [&](int k0, int bf) {
        u16* lA = &SB[bf * 8192 + wave * 512];
        u16* lB = &SB[bf * 8192 + 4096 + wave * 512];
        glds16(gA + k0, lA);
        glds16(gA + (size_t)64 * K + k0, lA + 2048);
        glds16(gB + k0, lB);
        glds16(gB + (size_t)64 * K + k0, lB + 2048);
    };

    stage(0, 0);
    for (int it = 0; it < 32; ++it) {
        stage((((it + 1) & 31) << 5), (it + 1) & 1);
        asm volatile("s_waitcnt vmcnt(4)\n\ts_barrier" ::: "memory");

        const u16* Asb = &SB[(it & 1) * 8192];
        const u16* Bsb = Asb + 4096;
        bf16x8 af[4], bfr[4];
#pragma unroll
        for (int i = 0; i < 4; ++i)
            af[i] = *(const bf16x8*)&Asb[(wm + i * 16 + ln) * 32 + quad * 8];
#pragma unroll
        for (int j = 0; j < 4; ++j)
            bfr[j] = *(const bf16x8*)&Bsb[(wn + j * 16 + ln) * 32 + quad * 8];
#pragma unroll
        for (int i = 0; i < 4; ++i)
#pragma unroll
            for (int j = 0; j < 4; ++j)
                acc[i][j] = MFMA(af[i], bfr[j], acc[i][j], 0, 0, 0);

        asm volatile("s_barrier" ::: "memory");
    }
    asm volatile("s_waitcnt vmcnt(0)\n\ts_barrier" ::: "memory");

    // ---- epilogue ----
    const int part = bn >> 10;                       // 0=q 1=k 2=v
    const int headw = wave & 1;
    const int h0 = (bn & 1023) >> 6;
    const float SC = 0.18033688011112042f;           // 0.125 * log2(e)
    const int b = bm >> 11, tbase = bm & 2047;

    if (part == 2) {
#pragma unroll
        for (int i = 0; i < 4; ++i) {
            int tlb = wm + i * 16 + quad * 4;
#pragma unroll
            for (int j = 0; j < 4; ++j) {
                int d = j * 16 + ln;
                uint2 pk;
                pk.x = __builtin_amdgcn_perm(fbits(acc[i][j][1]), fbits(acc[i][j][0]), 0x07060302u);
                pk.y = __builtin_amdgcn_perm(fbits(acc[i][j][3]), fbits(acc[i][j][2]), 0x07060302u);
                *(uint2*)&Es[headw * 8192 + d * 128 + (tlb ^ (ln << 3))] = pk;
            }
        }
        __syncthreads();
#pragma unroll
        for (int c = 0; c < 8; ++c) {
            int cid = c * 256 + tid;
            int tc = cid & 15, d = (cid >> 4) & 63, hd = cid >> 10;
            uint4 v = *(const uint4*)&Es[hd * 8192 + d * 128 + ((tc ^ (d & 15)) << 3)];
            size_t dst = ((size_t)((b * 16 + h0 + hd) * 64 + d)) * 2048
                       + tbase + ((tc >> 3) << 6) + (((tc & 7) ^ (d & 7)) << 3);
            *(uint4*)&vt[dst] = v;
        }
        return;
    }

    const float* nw = (part == 0) ? qw : kw;
    float wv[4];
#pragma unroll
    for (int j = 0; j < 4; ++j) {
        int nd = j * 16 + ln;
        int od = ((nd & 31) << 1) | (nd >> 5);
        wv[j] = nw[od];
    }

    if (part == 0) {
#pragma unroll
        for (int i = 0; i < 4; ++i) {
            float oj[4][4];
#pragma unroll
            for (int r = 0; r < 4; ++r) {
                int tloc = wm + i * 16 + quad * 4 + r;
                int t = (bm + tloc) & 2047;
                float v0 = acc[i][0][r], v1 = acc[i][1][r];
                float v2 = acc[i][2][r], v3 = acc[i][3][r];
                float ss = v0 * v0 + v1 * v1 + v2 * v2 + v3 * v3;
                ss += __shfl_xor(ss, 1);
                ss += __shfl_xor(ss, 2);
                ss += __shfl_xor(ss, 4);
                ss += __shfl_xor(ss, 8);
                float g = rsqrtf(ss * (1.0f / 64.0f) + 1e-6f) * SC;
                float x0a = v0 * g * wv[0], x0b = v1 * g * wv[1];
                float x1a = v2 * g * wv[2], x1b = v3 * g * wv[3];
                float2 cs0 = csb[t * 32 + ln];
                float2 cs1 = csb[t * 32 + 16 + ln];
                oj[0][r] = x0a * cs0.x - x1a * cs0.y;
                oj[2][r] = x0a * cs0.y + x1a * cs0.x;
                oj[1][r] = x0b * cs1.x - x1b * cs1.y;
                oj[3][r] = x0b * cs1.y + x1b * cs1.x;
            }
            int tlb = wm + i * 16 + quad * 4;
#pragma unroll
            for (int j = 0; j < 4; ++j) {
                uint2 pk;
                pk.x = __builtin_amdgcn_perm(fbits(oj[j][1]), fbits(oj[j][0]), 0x07060302u);
                pk.y = __builtin_amdgcn_perm(fbits(oj[j][3]), fbits(oj[j][2]), 0x07060302u);
                *(uint2*)&Es[headw * 8192 + (j * 16 + ln) * 128 + (tlb ^ (ln << 3))] = pk;
            }
        }
        __syncthreads();
#pragma unroll
        for (int c = 0; c < 8; ++c) {
            int cid = c * 256 + tid;
            int tc = cid & 15, d = (cid >> 4) & 63, hd = cid >> 10;
            uint4 v = *(const uint4*)&Es[hd * 8192 + d * 128 + ((tc ^ (d & 15)) << 3)];
            size_t dst = ((size_t)((b * 16 + h0 + hd) * 64 + d)) * 2048 + tbase + tc * 8;
            *(uint4*)&q[dst] = v;
        }
        return;
    }

    // K: RMSNorm + RoPE, [t][d] staging with quarter swizzle
#pragma unroll
    for (int i = 0; i < 4; ++i) {
#pragma unroll
        for (int r = 0; r < 4; ++r) {
            int tloc = wm + i * 16 + quad * 4 + r;
            int t = (bm + tloc) & 2047;

            float v0 = acc[i][0][r], v1 = acc[i][1][r];
            float v2 = acc[i][2][r], v3 = acc[i][3][r];
            float ss = v0 * v0 + v1 * v1 + v2 * v2 + v3 * v3;
            ss += __shfl_xor(ss, 1);
            ss += __shfl_xor(ss, 2);
            ss += __shfl_xor(ss, 4);
            ss += __shfl_xor(ss, 8);
            float g = rsqrtf(ss * (1.0f / 64.0f) + 1e-6f);

            float x0a = v0 * g * wv[0], x0b = v1 * g * wv[1];
            float x1a = v2 * g * wv[2], x1b = v3 * g * wv[3];
            float2 cs0 = csb[t * 32 + ln];
            float2 cs1 = csb[t * 32 + 16 + ln];
            float o0 = x0a * cs0.x - x1a * cs0.y;
            float o2 = x0a * cs0.y + x1a * cs0.x;
            float o1 = x0b * cs1.x - x1b * cs1.y;
            float o3 = x0b * cs1.y + x1b * cs1.x;

            u16* e = &Es[headw * 8192 + tloc * 64 + ln];
            e[((0 ^ quad) << 4)] = f2bf(o0);
            e[((1 ^ quad) << 4)] = f2bf(o1);
            e[((2 ^ quad) << 4)] = f2bf(o2);
            e[((3 ^ quad) << 4)] = f2bf(o3);
        }
    }
    __syncthreads();
#pragma unroll
    for (int c = 0; c < 8; ++c) {
        int cid = c * 256 + tid;
        int dc = cid & 7, tloc = (cid >> 3) & 127, hd = cid >> 10;
        int q2 = (tloc >> 2) & 3;
        int sq = (dc >> 1) ^ q2;
        uint4 v = *(const uint4*)&Es[hd * 8192 + tloc * 64 + sq * 16 + (dc & 1) * 8];
        int gm = bm + tloc;
        int bb = gm >> 11, t = gm & 2047;
        size_t rb = ((size_t)((bb * 16 + h0 + hd) * 2048 + t)) * 64;
        *(uint4*)&k[rb + ((dc ^ (t & 7)) << 3)] = v;
    }
}

// ---------------- 64x128 bf16 GEMM (projection), dbuf staging + XCD swizzle ----------
// (r7 form, unchanged)
__global__ __launch_bounds__(256) void gemm64(
    const u16* __restrict__ A, const u16* __restrict__ B,
    float* __restrict__ C, int M, int N, int K)
{
    __shared__ alignas(16) u16 SB[2 * 6144];
    const int tid = threadIdx.x;
    const int lane = tid & 63;
    const int wave = tid >> 6;

    const int bid = blockIdx.y * 8 + blockIdx.x;     // 0..511
    const int xcd = bid & 7;
    const int t8  = bid >> 3;                        // 0..63
    const int bm = (xcd * 8 + (t8 >> 3)) * 64;
    const int bn = (t8 & 7) * 128;

    const int wm = (wave >> 1) * 32, wn = (wave & 1) * 64;
    const int ln = lane & 15, quad = lane >> 4;

    f32x4 acc[2][4] = {};

    const int srow = tid >> 2;
    const int scol = (tid & 3) * 8;
    const u16* gA = A + (size_t)(bm + srow) * K + scol;
    const u16* gB = B + (size_t)(bn + srow) * K + scol;

    auto stage = [&](int k0, int bf) {
        u16* lA = &SB[bf * 6144 + wave * 512];
        u16* lB = &SB[bf * 6144 + 2048 + wave * 512];
        glds16(gA + k0, lA);
        glds16(gB + k0, lB);
        glds16(gB + (size_t)64 * K + k0, lB + 2048);
    };

    stage(0, 0);
    for (int it = 0; it < 32; ++it) {
        stage((((it + 1) & 31) << 5), (it + 1) & 1);
        asm volatile("s_waitcnt vmcnt(3)\n\ts_barrier" ::: "memory");

        const u16* Asb = &SB[(it & 1) * 6144];
        const u16* Bsb = Asb + 2048;
        bf16x8 af[2], bfr[4];
#pragma unroll
        for (int i = 0; i < 2; ++i)
            af[i] = *(const bf16x8*)&Asb[(wm + i * 16 + ln) * 32 + quad * 8];
#pragma unroll
        for (int j = 0; j < 4; ++j)
            bfr[j] = *(const bf16x8*)&Bsb[(wn + j * 16 + ln) * 32 + quad * 8];
#pragma unroll
        for (int i = 0; i < 2; ++i)
#pragma unroll
            for (int j = 0; j < 4; ++j)
                acc[i][j] = MFMA(af[i], bfr[j], acc[i][j], 0, 0, 0);

        asm volatile("s_barrier" ::: "memory");
    }

#pragma unroll
    for (int i = 0; i < 2; ++i) {
#pragma unroll
        for (int r = 0; r < 4; ++r) {
            int gm = bm + wm + i * 16 + quad * 4 + r;
            float* Crow = C + (size_t)gm * N + bn + wn + ln;
#pragma unroll
            for (int j = 0; j < 4; ++j)
                Crow[j * 16] = acc[i][j][r];
        }
    }
}

// ---------------- flash attention: r8 structure + complementary-pi load balance ------
// (unmeasured: r10/r11 were container-acquisition failures; source audited hang-free —
//  pi in 0..15, bijective (pi,bh), block-uniform barrier counts, no inter-block deps.)
// Theory: block wall time = 32-pi iters (17..32). r8 dispatch stacked (p, p+8) per CU
// -> wall 42..56 iters, ~14% tail (r9: occupancy 34.6% < 50% cap). Remap round 2 to
// pi = 23-pr so each CU pairs (p, 15-p): wall = 49 everywhere. XCD-home preserved.
__global__ __launch_bounds__(512) void attn_kernel(
    const u16* __restrict__ Q, const u16* __restrict__ K,
    const u16* __restrict__ VT, u16* __restrict__ Y)
{
    __shared__ alignas(16) u16 Ks[2][64 * 64];
    __shared__ alignas(16) u16 Vs[2][64 * 64];
    __shared__ alignas(16) u16 Ps[8][16 * 80];

    const int tid = threadIdx.x;
    const int lane = tid & 63;
    const int wave = tid >> 6;          // 0..7
    const int ln = lane & 15, quad = lane >> 4;

    const int lin = blockIdx.y * 16 + blockIdx.x;   // 0..511, dispatch-linear
    const int xcd = lin & 7;
    const int slot = lin >> 3;                      // 0..63
    const int bh = xcd + ((slot & 3) << 3);         // 0..31: 4 heads per XCD
    const int pr = slot >> 2;                       // 0..15
    const int pi = (slot < 32) ? pr : (23 - pr);    // round 2: complementary pi

    const int qaIdx = pi, qbIdx = 31 - pi;
    const bool isB = wave >= 4;
    const int qidx = isB ? qbIdx : qaIdx;
    const int myq = qidx * 64 + (wave & 3) * 16;
    const size_t base = (size_t)bh * 2048 * 64;
    const u16* Kg = K + base;
    const u16* Vg = VT + base;
    const __bf16* Qg = (const __bf16*)(Q + base);   // (64 d, 2048 t) per head

    const int qt = myq + ln;
    bf16x8 qf0, qf1;
#pragma unroll
    for (int j = 0; j < 8; ++j) {
        qf0[j] = Qg[(size_t)(quad * 8 + j) * 2048 + qt];
        qf1[j] = Qg[(size_t)(32 + quad * 8 + j) * 2048 + qt];
    }

    f32x4 o[4] = {};
    float l = 0.0f;
    const int nstages = qbIdx + 1;
    const int sw = ln & 7;
    const int srow = wave * 8 + (lane >> 3);
    const int scol = (lane & 7) * 8;
    u16* Psw = &Ps[wave][0];

    auto prefetch = [&](int jb, int nb) {
        glds16(&Kg[(size_t)(jb + srow) * 64 + scol], &Ks[nb][wave * 512]);
        glds16(&Vg[(size_t)srow * 2048 + jb + scol], &Vs[nb][wave * 512]);
    };
    auto computeS = [&](f32x4* st, const u16* ksb) {
#pragma unroll
        for (int ct = 0; ct < 4; ++ct) {
            bf16x8 kf0 = *(const bf16x8*)&ksb[(ct * 16 + ln) * 64 + (quad ^ sw) * 8];
            bf16x8 kf1 = *(const bf16x8*)&ksb[(ct * 16 + ln) * 64 + ((4 + quad) ^ sw) * 8];
            f32x4 z = {};
            z = MFMA(kf0, qf0, z, 0, 0, 0);
            st[ct] = MFMA(kf1, qf1, z, 0, 0, 0);
        }
    };
    auto applyMask = [&](f32x4* st, int jb) {
        const int qg = myq + ln;
#pragma unroll
        for (int ct = 0; ct < 4; ++ct)
#pragma unroll
            for (int r = 0; r < 4; ++r)
                if (jb + ct * 16 + quad * 4 + r > qg) st[ct][r] = -1e30f;
    };

    // prologue: tile 0 resident, S[0] in registers
    prefetch(0, 0);
    asm volatile("s_waitcnt vmcnt(0)\n\ts_barrier" ::: "memory");
    f32x4 st[4];
    computeS(st, &Ks[0][0]);
    if (qidx == 0) applyMask(st, 0);

    for (int jt = 0; jt < nstages; ++jt) {
        const bool haveNext = (jt + 1 < nstages);
        if (haveNext) prefetch((jt + 1) * 64, (jt + 1) & 1);

        const bool curActive = isB || jt <= qaIdx;
        if (curActive) {
            float sum = 0.0f;
#pragma unroll
            for (int ct = 0; ct < 4; ++ct) {
                float e0 = exp2f(st[ct][0]), e1 = exp2f(st[ct][1]);
                float e2 = exp2f(st[ct][2]), e3 = exp2f(st[ct][3]);
                sum += (e0 + e1) + (e2 + e3);
                uint2 pk;
                pk.x = __builtin_amdgcn_perm(fbits(e1), fbits(e0), 0x07060302u);
                pk.y = __builtin_amdgcn_perm(fbits(e3), fbits(e2), 0x07060302u);
                *(uint2*)&Psw[ln * 80 + ct * 16 + quad * 4] = pk;
            }
            l += sum;   // per-lane partial; cross-quad reduce deferred to epilogue

            __builtin_amdgcn_s_waitcnt(0xC07F);  // lgkmcnt(0): own Ps writes visible
            bf16x8 pf0 = *(const bf16x8*)&Psw[ln * 80 + quad * 8];
            bf16x8 pf1 = *(const bf16x8*)&Psw[ln * 80 + 32 + quad * 8];
            const u16* vsb = &Vs[jt & 1][0];
            __builtin_amdgcn_s_setprio(1);
#pragma unroll
            for (int dt = 0; dt < 4; ++dt) {
                bf16x8 vf0 = *(const bf16x8*)&vsb[(dt * 16 + ln) * 64 + (quad ^ sw) * 8];
                bf16x8 vf1 = *(const bf16x8*)&vsb[(dt * 16 + ln) * 64 + ((4 + quad) ^ sw) * 8];
                o[dt] = MFMA(pf0, vf0, o[dt], 0, 0, 0);
                o[dt] = MFMA(pf1, vf1, o[dt], 0, 0, 0);
            }
            __builtin_amdgcn_s_setprio(0);
        }

        // single barrier: (a) own DMAs for tile jt+1 drained -> next reads safe;
        // (b) all waves past PV(jt) -> next iter's prefetch may overwrite buf jt&1.
        asm volatile("s_waitcnt vmcnt(0)\n\ts_barrier" ::: "memory");

        const bool nextActive = haveNext && (isB || (jt + 1) <= qaIdx);
        if (nextActive) {
            __builtin_amdgcn_s_setprio(1);
            computeS(st, &Ks[(jt + 1) & 1][0]);
            __builtin_amdgcn_s_setprio(0);
            if (jt + 1 == qidx) applyMask(st, (jt + 1) * 64);
        }
    }

    // deferred l reduction: sum the 4 quad partials per q-column
    l += __shfl_xor(l, 16);
    l += __shfl_xor(l, 32);

    const int b = bh >> 4, h = bh & 15;
#pragma unroll
    for (int r = 0; r < 4; ++r) {
        float lr = __shfl(l, (lane & 48) + quad * 4 + r);
        float inv = 1.0f / lr;
        int gq = myq + quad * 4 + r;
        size_t yb = ((size_t)(b * 2048 + gq)) * 1024 + h * 64 + ln;
#pragma unroll
        for (int dt = 0; dt < 4; ++dt)
            Y[yb + dt * 16] = f2bf(o[dt][r] * inv);
    }
}

extern "C" void kernel_launch(void* const* d_in, const int* in_sizes, int n_in,
                              void* d_out, int out_size, void* d_ws, size_t ws_size,
                              hipStream_t stream) {
    const float* x      = (const float*)d_in[0];
    const float* fcos   = (const float*)d_in[1];
    const float* fsin   = (const float*)d_in[2];
    const float* w_attn = (const float*)d_in[3];
    const float* w_proj = (const float*)d_in[4];
    const float* qw     = (const float*)d_in[5];
    const float* kw     = (const float*)d_in[6];
    float* out = (float*)d_out;

    char* ws = (char*)d_ws;
    u16*    xb  = (u16*)(ws + 0);          //  8 MB  x bf16; aliased as yb after gemm_qkv
    u16*    yb  = (u16*)(ws + 0);
    u16*    wab = (u16*)(ws + 8388608);    //  6 MB  w_attn bf16 (q/k rows permuted)
    u16*    wpb = (u16*)(ws + 14680064);   //  2 MB  w_proj bf16
    u16*    qb  = (u16*)(ws + 16777216);   //  8 MB  q bf16 (B,H,64,2048), pre-scaled, perm-d
    u16*    kb  = (u16*)(ws + 25165824);   //  8 MB  k bf16 swizzled, perm-d
    u16*    vtb = (u16*)(ws + 33554432);   //  8 MB  v^T bf16 swizzled
    float2* csb = (float2*)(ws + 41943040);// 512 KB cos/sin interleaved table

    castbf3<<<8448, 256, 0, stream>>>(x, xb, w_attn, wab, w_proj, wpb, fcos, fsin, csb);

    gemm_qkv<<<dim3(24, 32), 256, 0, stream>>>(xb, wab, csb, qw, kw, qb, kb, vtb);

    attn_kernel<<<dim3(16, 32), 512, 0, stream>>>(qb, kb, vtb, yb);

    gemm64<<<dim3(8, 64), 256, 0, stream>>>(yb, wpb, out, 4096, 1024, 1024);
}